// Round 13
// baseline (147.893 us; speedup 1.0000x reference)
//
#include <hip/hip_runtime.h>

typedef __bf16 bf16;
typedef __bf16 bf16x8 __attribute__((ext_vector_type(8)));
typedef __bf16 bf16x4 __attribute__((ext_vector_type(4)));
typedef float f32x4 __attribute__((ext_vector_type(4)));

#define AS1(p) ((const __attribute__((address_space(1))) void*)(p))
#define AS3(p) ((__attribute__((address_space(3))) void*)(p))

__device__ __forceinline__ float sigm(float x) {
    return 1.f / (1.f + __expf(-x));
}
__device__ __forceinline__ float tanh_fast(float x) {
    float xx = fminf(fmaxf(x, -15.f), 15.f);
    float e = __expf(2.f * xx);
    return (e - 1.f) / (e + 1.f);
}
__device__ __forceinline__ bf16x8 pack8(float4 a, float4 b) {
    bf16x8 r;
    r[0] = (bf16)a.x; r[1] = (bf16)a.y; r[2] = (bf16)a.z; r[3] = (bf16)a.w;
    r[4] = (bf16)b.x; r[5] = (bf16)b.y; r[6] = (bf16)b.z; r[7] = (bf16)b.w;
    return r;
}

// ---------------------------------------------------------------------------
// Setup (verified R1/R5): bf16 weight copies.
//  Wcat [256][224] = [Wp | Wa | Wv] along K.
//  Wih_p/Whh_p [768][256]: gate-permuted rows. Permuted col c = chunk*48 +
//  gate*16 + jj maps to old row gate*256 + (chunk*16 + jj).
// ---------------------------------------------------------------------------
__global__ __launch_bounds__(256) void setup_weights(
    const float* __restrict__ Wp, const float* __restrict__ Wa, const float* __restrict__ Wv,
    const float* __restrict__ W_ih, const float* __restrict__ b_ih,
    const float* __restrict__ W_hh, const float* __restrict__ b_hh,
    bf16* __restrict__ Wcat, bf16* __restrict__ Wih_p, bf16* __restrict__ Whh_p,
    float* __restrict__ bih_p, float* __restrict__ bhh_p)
{
    int idx = blockIdx.x * 256 + threadIdx.x;
    if (idx < 256 * 224) {
        int out = idx / 224, k = idx % 224;
        float v = (k < 128) ? Wp[out * 128 + k]
                : (k < 192) ? Wa[out * 64 + (k - 128)]
                            : Wv[out * 32 + (k - 192)];
        Wcat[idx] = (bf16)v;
    }
    int i2 = idx - 256 * 224;
    if (i2 >= 0 && i2 < 768 * 256) {
        int c = i2 >> 8, k = i2 & 255;
        int chunk = c / 48, gate = (c % 48) / 16, jj = c % 16;
        int oldrow = gate * 256 + chunk * 16 + jj;
        Wih_p[i2] = (bf16)W_ih[oldrow * 256 + k];
        Whh_p[i2] = (bf16)W_hh[oldrow * 256 + k];
        if (k == 0) { bih_p[c] = b_ih[oldrow]; bhh_p[c] = b_hh[oldrow]; }
    }
}

// ---------------------------------------------------------------------------
// K1 (verified R1/R5): emb[slot][256] = x_cat(slot) @ Wcat^T + bias(type).
// ---------------------------------------------------------------------------
__global__ __launch_bounds__(256) void emb_kernel(
    const float* __restrict__ px, const float* __restrict__ ax_, const float* __restrict__ vx,
    const float* __restrict__ bp, const float* __restrict__ ba, const float* __restrict__ bv,
    const int* __restrict__ type_ids, const int* __restrict__ node_ids,
    const bf16* __restrict__ Wcat, bf16* __restrict__ emb)
{
    __shared__ bf16 At[32 * 232];
    __shared__ float biasl[768];
    const int tid = threadIdx.x;

    biasl[tid] = bp[tid];
    biasl[256 + tid] = ba[tid];
    biasl[512 + tid] = bv[tid];

    unsigned int* Az = (unsigned int*)At;
    #pragma unroll
    for (int i = 0; i < 15; i++) { int z = i * 256 + tid; if (z < 3712) Az[z] = 0u; }
    __syncthreads();

    const int slot0 = blockIdx.x * 32;
    {
        const int s = tid >> 3, g = tid & 7;
        const int slot = slot0 + s;
        const int t = type_ids[slot];
        const long n = (long)node_ids[slot];
        bf16* Arow = At + s * 232;
        if (t == 0) {
            const float4* src = (const float4*)(px + n * 128);
            float4 v0 = src[g * 4 + 0], v1 = src[g * 4 + 1], v2 = src[g * 4 + 2], v3 = src[g * 4 + 3];
            *(bf16x8*)(Arow + 16 * g) = pack8(v0, v1);
            *(bf16x8*)(Arow + 16 * g + 8) = pack8(v2, v3);
        } else if (t == 1) {
            const float4* src = (const float4*)(ax_ + n * 64);
            float4 v0 = src[g * 2 + 0], v1 = src[g * 2 + 1];
            *(bf16x8*)(Arow + 128 + 8 * g) = pack8(v0, v1);
        } else {
            float4 v0 = ((const float4*)(vx + n * 32))[g];
            bf16x4 r4; r4[0] = (bf16)v0.x; r4[1] = (bf16)v0.y; r4[2] = (bf16)v0.z; r4[3] = (bf16)v0.w;
            *(bf16x4*)(Arow + 192 + 4 * g) = r4;
        }
    }
    __syncthreads();

    const int w = tid >> 6, lane = tid & 63, l15 = lane & 15, l4 = lane >> 4;
    f32x4 zv = {0.f, 0.f, 0.f, 0.f};
    f32x4 acc[2][4];
    #pragma unroll
    for (int i = 0; i < 2; i++)
        #pragma unroll
        for (int j = 0; j < 4; j++) acc[i][j] = zv;

    #pragma unroll
    for (int k0 = 0; k0 < 224; k0 += 32) {
        bf16x8 a[2], b[4];
        #pragma unroll
        for (int am = 0; am < 2; am++) {
            int r = 16 * am + l15;
            a[am] = *(const bf16x8*)(At + r * 232 + k0 + 8 * l4);
        }
        #pragma unroll
        for (int bn = 0; bn < 4; bn++) {
            int o = 64 * w + 16 * bn + l15;
            b[bn] = *(const bf16x8*)(Wcat + o * 224 + k0 + 8 * l4);
        }
        #pragma unroll
        for (int am = 0; am < 2; am++)
            #pragma unroll
            for (int bn = 0; bn < 4; bn++)
                acc[am][bn] = __builtin_amdgcn_mfma_f32_16x16x32_bf16(a[am], b[bn], acc[am][bn], 0, 0, 0);
    }

    #pragma unroll
    for (int am = 0; am < 2; am++)
        #pragma unroll
        for (int bn = 0; bn < 4; bn++) {
            int o = 64 * w + 16 * bn + l15;
            #pragma unroll
            for (int r = 0; r < 4; r++) {
                int slot = slot0 + 16 * am + 4 * l4 + r;
                int t = type_ids[slot];
                emb[((size_t)slot << 8) + o] = (bf16)(acc[am][bn][r] + biasl[t * 256 + o]);
            }
        }
}

// ---------------------------------------------------------------------------
// K2 (verified R12): gx = emb @ Wih_p^T + bih_p, 128x96 tile + step-0 fold.
// ---------------------------------------------------------------------------
__global__ __launch_bounds__(256) void gx_kernel(
    const bf16* __restrict__ Am, const bf16* __restrict__ Wih_p,
    const float* __restrict__ bih_p, const float* __restrict__ bhh_p,
    const int* __restrict__ lengths, bf16* __restrict__ gx,
    bf16* __restrict__ h1b)
{
    __shared__ bf16 At[128 * 64];
    __shared__ bf16 Bt[96 * 64];
    const int tid = threadIdx.x;
    const int row0 = blockIdx.x * 128;
    const int c0 = blockIdx.y * 96;
    const int w = tid >> 6, lane = tid & 63, l15 = lane & 15, l4 = lane >> 4;
    const int wm = w >> 1, wn = w & 1;

    f32x4 zv = {0.f, 0.f, 0.f, 0.f};
    f32x4 acc[4][3];
    #pragma unroll
    for (int i = 0; i < 4; i++)
        #pragma unroll
        for (int j = 0; j < 3; j++) acc[i][j] = zv;

    for (int k0 = 0; k0 < 256; k0 += 64) {
        #pragma unroll
        for (int i = 0; i < 4; i++) {
            int g = i * 256 + tid; int r = g >> 3, s = g & 7;
            const bf16* src = Am + ((size_t)(row0 + r) << 8) + k0 + ((s ^ (r & 7)) << 3);
            __builtin_amdgcn_global_load_lds(AS1(src), AS3(At + g * 8), 16, 0, 0);
        }
        #pragma unroll
        for (int i = 0; i < 3; i++) {
            int g = i * 256 + tid; int r = g >> 3, s = g & 7;
            const bf16* src = Wih_p + ((size_t)(c0 + r) << 8) + k0 + ((s ^ (r & 7)) << 3);
            __builtin_amdgcn_global_load_lds(AS1(src), AS3(Bt + g * 8), 16, 0, 0);
        }
        __syncthreads();
        #pragma unroll
        for (int kk = 0; kk < 64; kk += 32) {
            int sbase = kk >> 3;
            bf16x8 a[4], b[3];
            #pragma unroll
            for (int am = 0; am < 4; am++) {
                int r = 64 * wm + 16 * am + l15;
                a[am] = *(const bf16x8*)(At + r * 64 + (((sbase + l4) ^ (r & 7)) << 3));
            }
            #pragma unroll
            for (int bn = 0; bn < 3; bn++) {
                int c = 48 * wn + 16 * bn + l15;
                b[bn] = *(const bf16x8*)(Bt + c * 64 + (((sbase + l4) ^ (c & 7)) << 3));
            }
            #pragma unroll
            for (int am = 0; am < 4; am++)
                #pragma unroll
                for (int bn = 0; bn < 3; bn++)
                    acc[am][bn] = __builtin_amdgcn_mfma_f32_16x16x32_bf16(a[am], b[bn], acc[am][bn], 0, 0, 0);
        }
        __syncthreads();
    }

    const int cbase = c0 + 48 * wn + l15;
    float bi[3];
    #pragma unroll
    for (int bn = 0; bn < 3; bn++) bi[bn] = bih_p[cbase + 16 * bn];

    #pragma unroll
    for (int am = 0; am < 4; am++)
        #pragma unroll
        for (int bn = 0; bn < 3; bn++) {
            int c = cbase + 16 * bn;
            #pragma unroll
            for (int r = 0; r < 4; r++) {
                int row = row0 + 64 * wm + 16 * am + 4 * l4 + r;
                gx[(size_t)row * 768 + c] = (bf16)(acc[am][bn][r] + bi[bn]);
            }
        }

    // step-0 GRU fold (verified R12): rows row%8==0 -> r=0, l4 even
    if ((l4 & 1) == 0) {
        const float bh0 = bhh_p[cbase], bh1 = bhh_p[cbase + 16], bh2 = bhh_p[cbase + 32];
        const int j = ((blockIdx.y * 2 + wn) << 4) + l15;
        #pragma unroll
        for (int am = 0; am < 4; am++) {
            int row = row0 + 64 * wm + 16 * am + 4 * l4;
            int path = row >> 3;
            float xr = acc[am][0][0] + bi[0];
            float xz = acc[am][1][0] + bi[1];
            float xn = acc[am][2][0] + bi[2];
            float rr = sigm(xr + bh0);
            float zz = sigm(xz + bh1);
            float nn = tanh_fast(xn + rr * bh2);
            float hnew = (0 < lengths[path]) ? (1.f - zz) * nn : 0.f;
            h1b[((size_t)path << 8) + j] = (bf16)hnew;
        }
    }
}

// ---------------------------------------------------------------------------
// K3 (R13): ALL GRU steps 1..7 in ONE ordinary launch.  Grid 256 = 1 block/CU
// (LB(256,1): full VGPR budget).  Block owns 16 paths x ALL 768 gate cols ->
// recurrence is block-local; only __syncthreads() between steps.  h ping-pongs
// in LDS (bf16, R3-verified swizzle); hold carried unrounded in registers.
// B-fragments (Whh) read direct from L2 each step: each dwordx4 frag-load
// touches 16 fully-consumed 64B lines; addresses identical every step.
// Wave w: cols [192w,+192) = 12 N-frags; per step 8 kc-chunks x 12 MFMA.
// Final h written to h0b (global) at l==7 for cls.
// ---------------------------------------------------------------------------
__global__ __launch_bounds__(256, 1) void gru_all(
    const bf16* __restrict__ h1b, const bf16* __restrict__ Whh_p,
    const float* __restrict__ bhh_p, const bf16* __restrict__ gx,
    const int* __restrict__ lengths, bf16* __restrict__ h0b)
{
    __shared__ bf16 hb[2][16 * 256];   // 2 x 8KB, swizzled [row][slot^(row&7)]
    const int tid = threadIdx.x;
    const int w = tid >> 6, lane = tid & 63, l15 = lane & 15, l4 = lane >> 4;
    const int row0 = blockIdx.x * 16;

    // per-thread constants
    int len_[4];
    #pragma unroll
    for (int r = 0; r < 4; r++) len_[r] = lengths[row0 + 4 * l4 + r];

    float bh0[4], bh1[4], bh2[4];
    #pragma unroll
    for (int g = 0; g < 4; g++) {
        int cb = 192 * w + 48 * g + l15;
        bh0[g] = bhh_p[cb]; bh1[g] = bhh_p[cb + 16]; bh2[g] = bhh_p[cb + 32];
    }

    // hreg: this thread's own h values (rows 4*l4+r, j=(4w+g)*16+l15), fp32
    float hreg[4][4];
    #pragma unroll
    for (int g = 0; g < 4; g++) {
        int j = (4 * w + g) * 16 + l15;
        #pragma unroll
        for (int r = 0; r < 4; r++)
            hreg[g][r] = (float)h1b[((size_t)(row0 + 4 * l4 + r) << 8) + j];
    }

    // stage h(step0) -> hb[0] (swizzled)
    {
        int row = tid >> 4, jg = tid & 15;
        const bf16* src = h1b + ((size_t)(row0 + row) << 8) + jg * 16;
        #pragma unroll
        for (int s = 0; s < 2; s++) {
            bf16x8 v = *(const bf16x8*)(src + 8 * s);
            int slot = 2 * jg + s;
            *(bf16x8*)(&hb[0][row * 256 + ((slot ^ (row & 7)) << 3)]) = v;
        }
    }

    // 12 B-operand base pointers (N-frag bn: cols 192w+16bn+l15, k-off 8*l4)
    const bf16* Bp[12];
    #pragma unroll
    for (int bn = 0; bn < 12; bn++)
        Bp[bn] = Whh_p + ((size_t)(192 * w + 16 * bn + l15) << 8) + 8 * l4;

    __syncthreads();

    int cur = 0;
    for (int l = 1; l < 8; l++) {
        // hoisted gate loads (complete under the K-loop)
        float xr_[4][4], xz_[4][4], xn_[4][4];
        #pragma unroll
        for (int r = 0; r < 4; r++) {
            const bf16* gxp = gx + ((size_t)((row0 + 4 * l4 + r) * 8 + l)) * 768
                            + 192 * w + l15;
            #pragma unroll
            for (int g = 0; g < 4; g++) {
                xr_[g][r] = (float)gxp[48 * g];
                xz_[g][r] = (float)gxp[48 * g + 16];
                xn_[g][r] = (float)gxp[48 * g + 32];
            }
        }

        f32x4 zv = {0.f, 0.f, 0.f, 0.f};
        f32x4 acc[12];
        #pragma unroll
        for (int bn = 0; bn < 12; bn++) acc[bn] = zv;

        #pragma unroll
        for (int kc = 0; kc < 8; kc++) {
            bf16x8 a = *(const bf16x8*)(&hb[cur][l15 * 256
                        + (((kc * 4 + l4) ^ (l15 & 7)) << 3)]);
            #pragma unroll
            for (int bn = 0; bn < 12; bn++) {
                bf16x8 b = *(const bf16x8*)(Bp[bn] + kc * 32);
                acc[bn] = __builtin_amdgcn_mfma_f32_16x16x32_bf16(a, b, acc[bn], 0, 0, 0);
            }
        }

        // fused gate epilogue; write h(l) to other LDS buffer (+global at l=7)
        #pragma unroll
        for (int g = 0; g < 4; g++) {
            int j = (4 * w + g) * 16 + l15;
            int slot = j >> 3, jo = j & 7;
            #pragma unroll
            for (int r = 0; r < 4; r++) {
                int row = 4 * l4 + r;
                float rr = sigm(xr_[g][r] + acc[3 * g + 0][r] + bh0[g]);
                float zz = sigm(xz_[g][r] + acc[3 * g + 1][r] + bh1[g]);
                float nn = tanh_fast(xn_[g][r] + rr * (acc[3 * g + 2][r] + bh2[g]));
                float hp = hreg[g][r];
                float hnew = (l < len_[r]) ? ((1.f - zz) * nn + zz * hp) : hp;
                hreg[g][r] = hnew;
                hb[cur ^ 1][row * 256 + ((slot ^ (row & 7)) << 3) + jo] = (bf16)hnew;
                if (l == 7)
                    h0b[((size_t)(row0 + row) << 8) + j] = (bf16)hnew;
            }
        }
        cur ^= 1;
        __syncthreads();
    }
}

// ---------------------------------------------------------------------------
// K4 (verified R8): logits = h_final(bf16) @ Wc^T + bc
// ---------------------------------------------------------------------------
__global__ __launch_bounds__(256) void cls_kernel(
    const bf16* __restrict__ h, const float* __restrict__ Wc,
    const float* __restrict__ bc, float* __restrict__ out)
{
    __shared__ float Wl[8 * 260];
    int tid = threadIdx.x;
    for (int i = tid; i < 2048; i += 256) { int c = i >> 8, k = i & 255; Wl[c * 260 + k] = Wc[i]; }
    __syncthreads();
    int o = blockIdx.x * 256 + tid;
    int row = o >> 3, c = o & 7;
    const bf16x8* hr = (const bf16x8*)(h + ((size_t)row << 8));
    const float* wr = Wl + c * 260;
    float acc1 = 0.f;
    #pragma unroll 8
    for (int k = 0; k < 32; k++) {
        bf16x8 a = hr[k];
        const float* b = wr + 8 * k;
        acc1 += (float)a[0] * b[0] + (float)a[1] * b[1] + (float)a[2] * b[2] + (float)a[3] * b[3]
              + (float)a[4] * b[4] + (float)a[5] * b[5] + (float)a[6] * b[6] + (float)a[7] * b[7];
    }
    out[o] = acc1 + bc[c];
}

extern "C" void kernel_launch(void* const* d_in, const int* in_sizes, int n_in,
                              void* d_out, int out_size, void* d_ws, size_t ws_size,
                              hipStream_t stream) {
    if (n_in < 18) return;
    const float* paper_x  = (const float*)d_in[0];
    const float* author_x = (const float*)d_in[1];
    const float* venue_x  = (const float*)d_in[2];
    const float* Wp   = (const float*)d_in[3];
    const float* bp   = (const float*)d_in[4];
    const float* Wa   = (const float*)d_in[5];
    const float* ba   = (const float*)d_in[6];
    const float* Wv   = (const float*)d_in[7];
    const float* bv   = (const float*)d_in[8];
    const float* W_ih = (const float*)d_in[9];
    const float* b_ih = (const float*)d_in[10];
    const float* W_hh = (const float*)d_in[11];
    const float* b_hh = (const float*)d_in[12];
    const float* Wc   = (const float*)d_in[13];
    const float* bc   = (const float*)d_in[14];
    const int* type_ids = (const int*)d_in[15];
    const int* node_ids = (const int*)d_in[16];
    const int* lengths  = (const int*)d_in[17];

    char* ws = (char*)d_ws;
    size_t off = 0;
    bf16* Wcat  = (bf16*)(ws + off); off += (size_t)256 * 224 * 2;
    bf16* Wih_p = (bf16*)(ws + off); off += (size_t)768 * 256 * 2;
    bf16* Whh_p = (bf16*)(ws + off); off += (size_t)768 * 256 * 2;
    float* bih_p = (float*)(ws + off); off += 768 * 4;
    float* bhh_p = (float*)(ws + off); off += 768 * 4;
    off = (off + 255) & ~(size_t)255;
    bf16* emb = (bf16*)(ws + off); off += (size_t)32768 * 256 * 2;
    bf16* gx  = (bf16*)(ws + off); off += (size_t)32768 * 768 * 2;
    bf16* h0b = (bf16*)(ws + off); off += (size_t)4096 * 256 * 2;
    bf16* h1b = (bf16*)(ws + off); off += (size_t)4096 * 256 * 2;
    if (ws_size < off) return;

    setup_weights<<<992, 256, 0, stream>>>(Wp, Wa, Wv, W_ih, b_ih, W_hh, b_hh,
                                           Wcat, Wih_p, Whh_p, bih_p, bhh_p);
    emb_kernel<<<1024, 256, 0, stream>>>(paper_x, author_x, venue_x, bp, ba, bv,
                                         type_ids, node_ids, Wcat, emb);
    // gx + fused step 0 (writes h1b)
    gx_kernel<<<dim3(256, 8), 256, 0, stream>>>(emb, Wih_p, bih_p, bhh_p,
                                                lengths, gx, h1b);
    // steps 1..7, one launch, block-local recurrence; final h -> h0b
    gru_all<<<256, 256, 0, stream>>>(h1b, Whh_p, bhh_p, gx, lengths, h0b);

    cls_kernel<<<128, 256, 0, stream>>>(h0b, Wc, bc, (float*)d_out);
}

// Round 14
// 101.866 us; speedup vs baseline: 1.4518x; 1.4518x over previous
//
#include <hip/hip_runtime.h>

typedef __bf16 bf16;
typedef __bf16 bf16x8 __attribute__((ext_vector_type(8)));
typedef __bf16 bf16x4 __attribute__((ext_vector_type(4)));
typedef float f32x4 __attribute__((ext_vector_type(4)));

#define AS1(p) ((const __attribute__((address_space(1))) void*)(p))
#define AS3(p) ((__attribute__((address_space(3))) void*)(p))

__device__ __forceinline__ float sigm(float x) {
    return 1.f / (1.f + __expf(-x));
}
__device__ __forceinline__ float tanh_fast(float x) {
    float xx = fminf(fmaxf(x, -15.f), 15.f);
    float e = __expf(2.f * xx);
    return (e - 1.f) / (e + 1.f);
}
__device__ __forceinline__ bf16x8 pack8(float4 a, float4 b) {
    bf16x8 r;
    r[0] = (bf16)a.x; r[1] = (bf16)a.y; r[2] = (bf16)a.z; r[3] = (bf16)a.w;
    r[4] = (bf16)b.x; r[5] = (bf16)b.y; r[6] = (bf16)b.z; r[7] = (bf16)b.w;
    return r;
}

// ---------------------------------------------------------------------------
// Setup (verified R1/R5): bf16 weight copies.
//  Wcat [256][224] = [Wp | Wa | Wv] along K.
//  Wih_p/Whh_p [768][256]: gate-permuted rows. Permuted col c = chunk*48 +
//  gate*16 + jj maps to old row gate*256 + (chunk*16 + jj).
// ---------------------------------------------------------------------------
__global__ __launch_bounds__(256) void setup_weights(
    const float* __restrict__ Wp, const float* __restrict__ Wa, const float* __restrict__ Wv,
    const float* __restrict__ W_ih, const float* __restrict__ b_ih,
    const float* __restrict__ W_hh, const float* __restrict__ b_hh,
    bf16* __restrict__ Wcat, bf16* __restrict__ Wih_p, bf16* __restrict__ Whh_p,
    float* __restrict__ bih_p, float* __restrict__ bhh_p)
{
    int idx = blockIdx.x * 256 + threadIdx.x;
    if (idx < 256 * 224) {
        int out = idx / 224, k = idx % 224;
        float v = (k < 128) ? Wp[out * 128 + k]
                : (k < 192) ? Wa[out * 64 + (k - 128)]
                            : Wv[out * 32 + (k - 192)];
        Wcat[idx] = (bf16)v;
    }
    int i2 = idx - 256 * 224;
    if (i2 >= 0 && i2 < 768 * 256) {
        int c = i2 >> 8, k = i2 & 255;
        int chunk = c / 48, gate = (c % 48) / 16, jj = c % 16;
        int oldrow = gate * 256 + chunk * 16 + jj;
        Wih_p[i2] = (bf16)W_ih[oldrow * 256 + k];
        Whh_p[i2] = (bf16)W_hh[oldrow * 256 + k];
        if (k == 0) { bih_p[c] = b_ih[oldrow]; bhh_p[c] = b_hh[oldrow]; }
    }
}

// ---------------------------------------------------------------------------
// K1 (verified R1/R5): emb[slot][256] = x_cat(slot) @ Wcat^T + bias(type).
// ---------------------------------------------------------------------------
__global__ __launch_bounds__(256) void emb_kernel(
    const float* __restrict__ px, const float* __restrict__ ax_, const float* __restrict__ vx,
    const float* __restrict__ bp, const float* __restrict__ ba, const float* __restrict__ bv,
    const int* __restrict__ type_ids, const int* __restrict__ node_ids,
    const bf16* __restrict__ Wcat, bf16* __restrict__ emb)
{
    __shared__ bf16 At[32 * 232];
    __shared__ float biasl[768];
    const int tid = threadIdx.x;

    biasl[tid] = bp[tid];
    biasl[256 + tid] = ba[tid];
    biasl[512 + tid] = bv[tid];

    unsigned int* Az = (unsigned int*)At;
    #pragma unroll
    for (int i = 0; i < 15; i++) { int z = i * 256 + tid; if (z < 3712) Az[z] = 0u; }
    __syncthreads();

    const int slot0 = blockIdx.x * 32;
    {
        const int s = tid >> 3, g = tid & 7;
        const int slot = slot0 + s;
        const int t = type_ids[slot];
        const long n = (long)node_ids[slot];
        bf16* Arow = At + s * 232;
        if (t == 0) {
            const float4* src = (const float4*)(px + n * 128);
            float4 v0 = src[g * 4 + 0], v1 = src[g * 4 + 1], v2 = src[g * 4 + 2], v3 = src[g * 4 + 3];
            *(bf16x8*)(Arow + 16 * g) = pack8(v0, v1);
            *(bf16x8*)(Arow + 16 * g + 8) = pack8(v2, v3);
        } else if (t == 1) {
            const float4* src = (const float4*)(ax_ + n * 64);
            float4 v0 = src[g * 2 + 0], v1 = src[g * 2 + 1];
            *(bf16x8*)(Arow + 128 + 8 * g) = pack8(v0, v1);
        } else {
            float4 v0 = ((const float4*)(vx + n * 32))[g];
            bf16x4 r4; r4[0] = (bf16)v0.x; r4[1] = (bf16)v0.y; r4[2] = (bf16)v0.z; r4[3] = (bf16)v0.w;
            *(bf16x4*)(Arow + 192 + 4 * g) = r4;
        }
    }
    __syncthreads();

    const int w = tid >> 6, lane = tid & 63, l15 = lane & 15, l4 = lane >> 4;
    f32x4 zv = {0.f, 0.f, 0.f, 0.f};
    f32x4 acc[2][4];
    #pragma unroll
    for (int i = 0; i < 2; i++)
        #pragma unroll
        for (int j = 0; j < 4; j++) acc[i][j] = zv;

    #pragma unroll
    for (int k0 = 0; k0 < 224; k0 += 32) {
        bf16x8 a[2], b[4];
        #pragma unroll
        for (int am = 0; am < 2; am++) {
            int r = 16 * am + l15;
            a[am] = *(const bf16x8*)(At + r * 232 + k0 + 8 * l4);
        }
        #pragma unroll
        for (int bn = 0; bn < 4; bn++) {
            int o = 64 * w + 16 * bn + l15;
            b[bn] = *(const bf16x8*)(Wcat + o * 224 + k0 + 8 * l4);
        }
        #pragma unroll
        for (int am = 0; am < 2; am++)
            #pragma unroll
            for (int bn = 0; bn < 4; bn++)
                acc[am][bn] = __builtin_amdgcn_mfma_f32_16x16x32_bf16(a[am], b[bn], acc[am][bn], 0, 0, 0);
    }

    #pragma unroll
    for (int am = 0; am < 2; am++)
        #pragma unroll
        for (int bn = 0; bn < 4; bn++) {
            int o = 64 * w + 16 * bn + l15;
            #pragma unroll
            for (int r = 0; r < 4; r++) {
                int slot = slot0 + 16 * am + 4 * l4 + r;
                int t = type_ids[slot];
                emb[((size_t)slot << 8) + o] = (bf16)(acc[am][bn][r] + biasl[t * 256 + o]);
            }
        }
}

// ---------------------------------------------------------------------------
// K2 (verified R12): gx = emb @ Wih_p^T + bih_p, 128x96 tile + step-0 fold.
// (Single-buffered: dbuf here would drop occupancy 3->2 blocks/CU — m132 trap.)
// ---------------------------------------------------------------------------
__global__ __launch_bounds__(256) void gx_kernel(
    const bf16* __restrict__ Am, const bf16* __restrict__ Wih_p,
    const float* __restrict__ bih_p, const float* __restrict__ bhh_p,
    const int* __restrict__ lengths, bf16* __restrict__ gx,
    bf16* __restrict__ h1b)
{
    __shared__ bf16 At[128 * 64];
    __shared__ bf16 Bt[96 * 64];
    const int tid = threadIdx.x;
    const int row0 = blockIdx.x * 128;
    const int c0 = blockIdx.y * 96;
    const int w = tid >> 6, lane = tid & 63, l15 = lane & 15, l4 = lane >> 4;
    const int wm = w >> 1, wn = w & 1;

    f32x4 zv = {0.f, 0.f, 0.f, 0.f};
    f32x4 acc[4][3];
    #pragma unroll
    for (int i = 0; i < 4; i++)
        #pragma unroll
        for (int j = 0; j < 3; j++) acc[i][j] = zv;

    for (int k0 = 0; k0 < 256; k0 += 64) {
        #pragma unroll
        for (int i = 0; i < 4; i++) {
            int g = i * 256 + tid; int r = g >> 3, s = g & 7;
            const bf16* src = Am + ((size_t)(row0 + r) << 8) + k0 + ((s ^ (r & 7)) << 3);
            __builtin_amdgcn_global_load_lds(AS1(src), AS3(At + g * 8), 16, 0, 0);
        }
        #pragma unroll
        for (int i = 0; i < 3; i++) {
            int g = i * 256 + tid; int r = g >> 3, s = g & 7;
            const bf16* src = Wih_p + ((size_t)(c0 + r) << 8) + k0 + ((s ^ (r & 7)) << 3);
            __builtin_amdgcn_global_load_lds(AS1(src), AS3(Bt + g * 8), 16, 0, 0);
        }
        __syncthreads();
        #pragma unroll
        for (int kk = 0; kk < 64; kk += 32) {
            int sbase = kk >> 3;
            bf16x8 a[4], b[3];
            #pragma unroll
            for (int am = 0; am < 4; am++) {
                int r = 64 * wm + 16 * am + l15;
                a[am] = *(const bf16x8*)(At + r * 64 + (((sbase + l4) ^ (r & 7)) << 3));
            }
            #pragma unroll
            for (int bn = 0; bn < 3; bn++) {
                int c = 48 * wn + 16 * bn + l15;
                b[bn] = *(const bf16x8*)(Bt + c * 64 + (((sbase + l4) ^ (c & 7)) << 3));
            }
            #pragma unroll
            for (int am = 0; am < 4; am++)
                #pragma unroll
                for (int bn = 0; bn < 3; bn++)
                    acc[am][bn] = __builtin_amdgcn_mfma_f32_16x16x32_bf16(a[am], b[bn], acc[am][bn], 0, 0, 0);
        }
        __syncthreads();
    }

    const int cbase = c0 + 48 * wn + l15;
    float bi[3];
    #pragma unroll
    for (int bn = 0; bn < 3; bn++) bi[bn] = bih_p[cbase + 16 * bn];

    #pragma unroll
    for (int am = 0; am < 4; am++)
        #pragma unroll
        for (int bn = 0; bn < 3; bn++) {
            int c = cbase + 16 * bn;
            #pragma unroll
            for (int r = 0; r < 4; r++) {
                int row = row0 + 64 * wm + 16 * am + 4 * l4 + r;
                gx[(size_t)row * 768 + c] = (bf16)(acc[am][bn][r] + bi[bn]);
            }
        }

    // step-0 GRU fold (verified R12): rows row%8==0 -> r=0, l4 even
    if ((l4 & 1) == 0) {
        const float bh0 = bhh_p[cbase], bh1 = bhh_p[cbase + 16], bh2 = bhh_p[cbase + 32];
        const int j = ((blockIdx.y * 2 + wn) << 4) + l15;
        #pragma unroll
        for (int am = 0; am < 4; am++) {
            int row = row0 + 64 * wm + 16 * am + 4 * l4;
            int path = row >> 3;
            float xr = acc[am][0][0] + bi[0];
            float xz = acc[am][1][0] + bi[1];
            float xn = acc[am][2][0] + bi[2];
            float rr = sigm(xr + bh0);
            float zz = sigm(xz + bh1);
            float nn = tanh_fast(xn + rr * bh2);
            float hnew = (0 < lengths[path]) ? (1.f - zz) * nn : 0.f;
            h1b[((size_t)path << 8) + j] = (bf16)hnew;
        }
    }
}

// ---------------------------------------------------------------------------
// K3 (R14): one GRU step (1..7).  R8-verified geometry (32x96, grid 128x8,
// 4 blocks/CU) + T3 minimum-2-phase prefetch: double-buffered LDS (32KB,
// still 4 blocks/CU), next chunk's global_load_lds issued BEFORE computing
// the current chunk, ONE barrier per chunk.  MFMA order unchanged -> bit-
// exact vs R12.
// ---------------------------------------------------------------------------
__global__ __launch_bounds__(256, 4) void gru_kernel(
    const bf16* __restrict__ hin_b,
    const bf16* __restrict__ Whh_p, const float* __restrict__ bhh_p,
    const bf16* __restrict__ gx, const int* __restrict__ lengths,
    bf16* __restrict__ hout_b, int step)
{
    __shared__ bf16 At[2][32 * 64];
    __shared__ bf16 Bt[2][96 * 64];
    const int tid = threadIdx.x;
    const int row0 = blockIdx.x * 32;
    const int c0 = blockIdx.y * 96;
    const int w = tid >> 6, lane = tid & 63, l15 = lane & 15, l4 = lane >> 4;
    const int wm = w >> 1, wn = w & 1;

    // ---- hoisted epilogue operands (complete under the K-loop) ----
    const int cbase = c0 + 48 * wn + l15;
    const int j = ((blockIdx.y * 2 + wn) << 4) + l15;
    float xr_[4], xz_[4], xn_[4], hold_[4];
    int len_[4];
    #pragma unroll
    for (int r = 0; r < 4; r++) {
        int row = row0 + 16 * wm + 4 * l4 + r;
        const bf16* gxp = gx + ((size_t)(row * 8 + step)) * 768 + cbase;
        xr_[r] = (float)gxp[0]; xz_[r] = (float)gxp[16]; xn_[r] = (float)gxp[32];
        hold_[r] = (float)hin_b[((size_t)row << 8) + j];
        len_[r] = lengths[row];
    }
    const float bh0 = bhh_p[cbase], bh1 = bhh_p[cbase + 16], bh2 = bhh_p[cbase + 32];

    f32x4 zv = {0.f, 0.f, 0.f, 0.f};
    f32x4 acc[3];
    #pragma unroll
    for (int i = 0; i < 3; i++) acc[i] = zv;

    // staging helper: chunk k0 -> buffer buf
    auto stage = [&](int buf, int k0) {
        {
            int g = tid; int r = g >> 3, s = g & 7;
            const bf16* src = hin_b + ((size_t)(row0 + r) << 8) + k0 + ((s ^ (r & 7)) << 3);
            __builtin_amdgcn_global_load_lds(AS1(src), AS3(&At[buf][g * 8]), 16, 0, 0);
        }
        #pragma unroll
        for (int i = 0; i < 3; i++) {
            int g = i * 256 + tid; int r = g >> 3, s = g & 7;
            const bf16* src = Whh_p + ((size_t)(c0 + r) << 8) + k0 + ((s ^ (r & 7)) << 3);
            __builtin_amdgcn_global_load_lds(AS1(src), AS3(&Bt[buf][g * 8]), 16, 0, 0);
        }
    };

    // prologue: stage chunk 0 -> buf 0 (barrier drains vmcnt)
    stage(0, 0);
    __syncthreads();

    #pragma unroll
    for (int c = 0; c < 4; c++) {
        const int cur = c & 1;
        // issue next chunk's loads BEFORE computing current (T3 prefetch)
        if (c < 3) stage(cur ^ 1, (c + 1) * 64);

        #pragma unroll
        for (int kk = 0; kk < 64; kk += 32) {
            int sbase = kk >> 3;
            bf16x8 a, b[3];
            {
                int r = 16 * wm + l15;
                a = *(const bf16x8*)(&At[cur][r * 64 + (((sbase + l4) ^ (r & 7)) << 3)]);
            }
            #pragma unroll
            for (int bn = 0; bn < 3; bn++) {
                int ccol = 48 * wn + 16 * bn + l15;
                b[bn] = *(const bf16x8*)(&Bt[cur][ccol * 64 + (((sbase + l4) ^ (ccol & 7)) << 3)]);
            }
            #pragma unroll
            for (int bn = 0; bn < 3; bn++)
                acc[bn] = __builtin_amdgcn_mfma_f32_16x16x32_bf16(a, b[bn], acc[bn], 0, 0, 0);
        }
        __syncthreads();   // drains this iteration's stage (vmcnt 0) + lds
    }

    #pragma unroll
    for (int r = 0; r < 4; r++) {
        int row = row0 + 16 * wm + 4 * l4 + r;
        float rr = sigm(xr_[r] + acc[0][r] + bh0);
        float zz = sigm(xz_[r] + acc[1][r] + bh1);
        float nn = tanh_fast(xn_[r] + rr * (acc[2][r] + bh2));
        float hnew = (step < len_[r]) ? ((1.f - zz) * nn + zz * hold_[r]) : hold_[r];
        hout_b[((size_t)row << 8) + j] = (bf16)hnew;
    }
}

// ---------------------------------------------------------------------------
// K4 (verified R8): logits = h_final(bf16) @ Wc^T + bc
// ---------------------------------------------------------------------------
__global__ __launch_bounds__(256) void cls_kernel(
    const bf16* __restrict__ h, const float* __restrict__ Wc,
    const float* __restrict__ bc, float* __restrict__ out)
{
    __shared__ float Wl[8 * 260];
    int tid = threadIdx.x;
    for (int i = tid; i < 2048; i += 256) { int c = i >> 8, k = i & 255; Wl[c * 260 + k] = Wc[i]; }
    __syncthreads();
    int o = blockIdx.x * 256 + tid;
    int row = o >> 3, c = o & 7;
    const bf16x8* hr = (const bf16x8*)(h + ((size_t)row << 8));
    const float* wr = Wl + c * 260;
    float acc1 = 0.f;
    #pragma unroll 8
    for (int k = 0; k < 32; k++) {
        bf16x8 a = hr[k];
        const float* b = wr + 8 * k;
        acc1 += (float)a[0] * b[0] + (float)a[1] * b[1] + (float)a[2] * b[2] + (float)a[3] * b[3]
              + (float)a[4] * b[4] + (float)a[5] * b[5] + (float)a[6] * b[6] + (float)a[7] * b[7];
    }
    out[o] = acc1 + bc[c];
}

extern "C" void kernel_launch(void* const* d_in, const int* in_sizes, int n_in,
                              void* d_out, int out_size, void* d_ws, size_t ws_size,
                              hipStream_t stream) {
    if (n_in < 18) return;
    const float* paper_x  = (const float*)d_in[0];
    const float* author_x = (const float*)d_in[1];
    const float* venue_x  = (const float*)d_in[2];
    const float* Wp   = (const float*)d_in[3];
    const float* bp   = (const float*)d_in[4];
    const float* Wa   = (const float*)d_in[5];
    const float* ba   = (const float*)d_in[6];
    const float* Wv   = (const float*)d_in[7];
    const float* bv   = (const float*)d_in[8];
    const float* W_ih = (const float*)d_in[9];
    const float* b_ih = (const float*)d_in[10];
    const float* W_hh = (const float*)d_in[11];
    const float* b_hh = (const float*)d_in[12];
    const float* Wc   = (const float*)d_in[13];
    const float* bc   = (const float*)d_in[14];
    const int* type_ids = (const int*)d_in[15];
    const int* node_ids = (const int*)d_in[16];
    const int* lengths  = (const int*)d_in[17];

    char* ws = (char*)d_ws;
    size_t off = 0;
    bf16* Wcat  = (bf16*)(ws + off); off += (size_t)256 * 224 * 2;
    bf16* Wih_p = (bf16*)(ws + off); off += (size_t)768 * 256 * 2;
    bf16* Whh_p = (bf16*)(ws + off); off += (size_t)768 * 256 * 2;
    float* bih_p = (float*)(ws + off); off += 768 * 4;
    float* bhh_p = (float*)(ws + off); off += 768 * 4;
    off = (off + 255) & ~(size_t)255;
    bf16* emb = (bf16*)(ws + off); off += (size_t)32768 * 256 * 2;
    bf16* gx  = (bf16*)(ws + off); off += (size_t)32768 * 768 * 2;
    bf16* h0b = (bf16*)(ws + off); off += (size_t)4096 * 256 * 2;
    bf16* h1b = (bf16*)(ws + off); off += (size_t)4096 * 256 * 2;
    if (ws_size < off) return;

    setup_weights<<<992, 256, 0, stream>>>(Wp, Wa, Wv, W_ih, b_ih, W_hh, b_hh,
                                           Wcat, Wih_p, Whh_p, bih_p, bhh_p);
    emb_kernel<<<1024, 256, 0, stream>>>(paper_x, author_x, venue_x, bp, ba, bv,
                                         type_ids, node_ids, Wcat, emb);
    // gx + fused step 0 (writes h1b)
    gx_kernel<<<dim3(256, 8), 256, 0, stream>>>(emb, Wih_p, bih_p, bhh_p,
                                                lengths, gx, h1b);

    // steps 1..7 ping-pong; final lands in h0b
    for (int l = 1; l < 8; l++) {
        const bf16* hib = (l & 1) ? h1b : h0b;
        bf16* hob = (l & 1) ? h0b : h1b;
        gru_kernel<<<dim3(128, 8), 256, 0, stream>>>(hib, Whh_p, bhh_p, gx,
                                                     lengths, hob, l);
    }
    cls_kernel<<<128, 256, 0, stream>>>(h0b, Wc, bc, (float*)d_out);
}